// Round 16
// baseline (37.159 us; speedup 1.0000x reference)
//
#include <hip/hip_runtime.h>

#define KA 50
#define KP 52
#define H 128
#define D 256
#define NBLK 256
#define BLOCK 1024
#define NG 8
#define RPT 7
#define STRD 136   // shorts; row stride for af/xi/hsum (272B: 16B-aligned, 2-way bank alias)

// B-fragment pack bases (units of 512-short fragments)
#define WS_WI 0
#define WS_WJ 32
#define WS_WR2 64
#define WS_WG 96
#define NFRAG 160

typedef __attribute__((ext_vector_type(8))) short bf16x8;
typedef __attribute__((ext_vector_type(4))) float f32x4;
typedef __attribute__((ext_vector_type(2))) float v2f;

__device__ __forceinline__ float bf2f(unsigned short u) {
  return __uint_as_float(((unsigned)u) << 16);
}
__device__ __forceinline__ unsigned short f2bf_rne(float f) {   // pack_weights only
  unsigned u = __float_as_uint(f);
  u = (u + 0x7FFFu + ((u >> 16) & 1u)) >> 16;
  return (unsigned short)u;
}
__device__ __forceinline__ unsigned short f2bf(float f) {   // RN ties-away, 2 ops
  return (unsigned short)((__float_as_uint(f) + 0x8000u) >> 16);
}
__device__ __forceinline__ int rli(int v, int l) {   // wave broadcast (SGPR/imm lane)
  return __builtin_amdgcn_readlane(v, l);
}
// atan2 via odd minimax poly on [0,1]; |err| ~1e-5 rad (<< bf16 quant of ang).
// Callers guarantee (x,y) != (0,0).
__device__ __forceinline__ float fast_atan2(float y, float x) {
  const float ax = fabsf(x), ay = fabsf(y);
  const float mx = fmaxf(ax, ay), mn = fminf(ax, ay);
  const float r  = mn * __builtin_amdgcn_rcpf(mx);
  const float r2 = r * r;
  float p = fmaf(r2, 0.0208351f, -0.0851330f);
  p = fmaf(r2, p, 0.1801410f);
  p = fmaf(r2, p, -0.3302995f);
  p = fmaf(r2, p, 0.9998660f);
  float th = r * p;
  if (ay > ax) th = 1.57079632679f - th;
  if (x < 0.f) th = 3.14159265359f - th;
  return copysignf(th, y);
}

// ---- pre-pass: pack weights into bf16 MFMA B-fragment order in d_ws ------
__global__ void pack_weights(const float* __restrict__ w_r1,
                             const float* __restrict__ w_r2,
                             const float* __restrict__ w_g,
                             unsigned short* __restrict__ wp) {
  const int t = blockIdx.x * 256 + threadIdx.x;
  if (t >= NFRAG * 64) return;
  const int f = t >> 6, lane = t & 63;
  const float* W; int rowbase, sf;
  if (f < 64)       { W = w_r1; rowbase = (f < 32) ? 0 : 128; sf = f & 31; }
  else if (f < 96)  { W = w_r2; rowbase = 0; sf = f - 64; }
  else              { W = w_g;  rowbase = 0; sf = f - 96; }
  const int kt = sf >> 3, ctl = sf & 7;
  const int col = ctl * 16 + (lane & 15);
  const int k0  = rowbase + kt * 32 + (lane >> 4) * 8;
  unsigned short v[8];
  #pragma unroll
  for (int j = 0; j < 8; ++j) v[j] = f2bf_rne(W[(k0 + j) * H + col]);
  #pragma unroll
  for (int j = 0; j < 8; ++j) wp[(size_t)t * 8 + j] = v[j];
}

struct alignas(16) Smem {
  unsigned short af[KP * STRD];    // agent_feat bf16 (rows 50,51 zeroed)
  unsigned short xi[KP * STRD];    // x_i bf16; agg after ph4; f32 scratch in ph6
  unsigned short xj[KP * H];       // x_j bf16, row-major [52][128]
  unsigned short hsum[KP * STRD];  // masked relu-sum over b, bf16
  float red[1024];
  float latent1[D];
  float s[KA][6];
  float m[64];                     // zero-padded
  float cnta[KP];
  float invden[KP];
  float cnt;
};

// phase-3 main loop: 3 rows, full b-range [0,50)
__device__ __forceinline__ void ph3_main(const Smem& sh, const unsigned* q0,
                                         const unsigned* q1, const v2f* base01,
                                         v2f* acc01, v2f wgd01, v2f wgan01,
                                         v2f wgs01, int c0) {
  #pragma unroll 10
  for (int b = 0; b < KA; ++b) {
    const unsigned xjp = *(const unsigned*)&sh.xj[b * H + c0];
    const v2f xj01 = { __uint_as_float(xjp << 16),
                       __uint_as_float(xjp & 0xFFFF0000u) };
    #pragma unroll
    for (int r = 0; r < 3; ++r) {
      const unsigned rq0 = (unsigned)rli((int)q0[r], b);
      const unsigned rq1 = (unsigned)rli((int)q1[r], b);
      const float dd = __uint_as_float(rq0 << 16);
      const float aa = __uint_as_float(rq0 & 0xFFFF0000u);
      const float ss = __uint_as_float(rq1 << 16);
      const float mm = __uint_as_float(rq1 & 0xFFFF0000u);
      v2f t = __builtin_elementwise_fma((v2f){dd, dd}, wgd01, base01[r] + xj01);
      t = __builtin_elementwise_fma((v2f){aa, aa}, wgan01, t);
      t = __builtin_elementwise_fma((v2f){ss, ss}, wgs01, t);
      t = __builtin_elementwise_max(t, (v2f){0.f, 0.f});
      acc01[r] = __builtin_elementwise_fma((v2f){mm, mm}, t, acc01[r]);
    }
  }
}

// phase-3 tail: one row, LEN b-iters starting at runtime wave-uniform bbeg
template <int LEN>
__device__ __forceinline__ void ph3_tail(const Smem& sh, int bbeg,
                                         unsigned q0t, unsigned q1t,
                                         v2f baset, v2f& acct,
                                         v2f wgd01, v2f wgan01, v2f wgs01,
                                         int c0) {
  #pragma unroll
  for (int bi = 0; bi < LEN; ++bi) {
    const int b = bbeg + bi;
    const unsigned xjp = *(const unsigned*)&sh.xj[b * H + c0];
    const v2f xj01 = { __uint_as_float(xjp << 16),
                       __uint_as_float(xjp & 0xFFFF0000u) };
    const unsigned rq0 = (unsigned)rli((int)q0t, b);
    const unsigned rq1 = (unsigned)rli((int)q1t, b);
    const float dd = __uint_as_float(rq0 << 16);
    const float aa = __uint_as_float(rq0 & 0xFFFF0000u);
    const float ss = __uint_as_float(rq1 << 16);
    const float mm = __uint_as_float(rq1 & 0xFFFF0000u);
    v2f t = __builtin_elementwise_fma((v2f){dd, dd}, wgd01, baset + xj01);
    t = __builtin_elementwise_fma((v2f){aa, aa}, wgan01, t);
    t = __builtin_elementwise_fma((v2f){ss, ss}, wgs01, t);
    t = __builtin_elementwise_max(t, (v2f){0.f, 0.f});
    acct = __builtin_elementwise_fma((v2f){mm, mm}, t, acct);
  }
}

__global__ void __launch_bounds__(BLOCK) rpe_kernel(
    const float* __restrict__ states, const float* __restrict__ masks,
    const float* __restrict__ w_a,  const float* __restrict__ b_a,
    const float* __restrict__ w_r1, const float* __restrict__ b_r1,
    const float* __restrict__ b_r2,
    const float* __restrict__ b_g,
    const float* __restrict__ w_f1, const float* __restrict__ b_f1,
    const float* __restrict__ w_f2, const float* __restrict__ b_f2,
    const unsigned short* __restrict__ wp,
    float* __restrict__ out) {
  __shared__ Smem sh;
  const int n = blockIdx.x;
  const int tid = threadIdx.x;
  const int c = tid & (H - 1);
  const int bg = tid >> 7;            // 0..7
  const int wid = tid >> 6, lane = tid & 63;
  const int ct = wid & 7;             // col tile 0..7 (MFMA phases)
  const int rtb = (wid >> 3) * 2;     // row tiles rtb, rtb+1
  const int fr = lane & 15;
  const int fkg = lane >> 4;
  const int col = ct * 16 + fr;

  // ---- top-level preloads (no LDS dependence) ----------------------------
  const float bac = b_a[c];
  const float wa0 = w_a[0*H+c], wa1 = w_a[1*H+c], wa2 = w_a[2*H+c];
  const float wa3 = w_a[3*H+c], wa4 = w_a[4*H+c], wa5 = w_a[5*H+c];
  const int c0 = 2 * lane;
  const v2f wgd01  = { w_r1[256*H + c0], w_r1[256*H + c0+1] };
  const v2f wgan01 = { w_r1[257*H + c0], w_r1[257*H + c0+1] };
  const v2f wgs01  = { w_r1[258*H + c0], w_r1[258*H + c0+1] };
  const v2f br101  = { b_r1[c0], b_r1[c0+1] };

  // ---------------- Phase 0: stage states, masks, zero pads ---------------
  {
    if (tid < KA * 6) ((float*)sh.s)[tid] = states[(size_t)n * (KA * 6) + tid];
    if (tid < 64) sh.m[tid] = (tid < KA) ? masks[(size_t)n * KA + tid] : 0.f;
    if (tid < 2 * H) {
      const int r5 = KA + (tid >> 7), cc = tid & (H - 1);
      sh.af[r5 * STRD + cc] = 0;
      sh.hsum[r5 * STRD + cc] = 0;
    }
  }
  __syncthreads();
  if (wid == 0) {                     // parallel mask count (lanes 50-63 are 0)
    float v = sh.m[lane];
    v += __shfl_xor(v, 1);  v += __shfl_xor(v, 2);  v += __shfl_xor(v, 4);
    v += __shfl_xor(v, 8);  v += __shfl_xor(v, 16); v += __shfl_xor(v, 32);
    if (lane == 0) sh.cnt = v;
  }

  // ---- Phase-3 geo hoist: lane b owns geo(a_rows, b), bf16-packed --------
  const int bl = (lane < KA) ? lane : (KA - 1);
  const float pbx = sh.s[bl][0], pby = sh.s[bl][1];
  const float pvx = sh.s[bl][2], pvy = sh.s[bl][3];
  const unsigned mbits = (sh.m[lane] != 0.f) ? 0x3F800000u : 0u;  // bf16 1.0 hi
  const bool hastail = (wid < 8);     // wave w: row 48+(w&1), chunk w>>1
  const int ar4 = 48 + (wid & 1);
  const int chunk = wid >> 1;         // 0..3 for tail waves
  const int bbeg = (chunk < 2) ? chunk * 13 : 26 + (chunk - 2) * 12;
  unsigned q0[3], q1[3], q0t = 0, q1t = 0;
  #pragma unroll
  for (int r = 0; r < 3; ++r) {
    const int ar = wid + 16 * r;       // <= 47
    const float rx  = pbx - sh.s[ar][0], ry  = pby - sh.s[ar][1];
    const float dvx = pvx - sh.s[ar][2], dvy = pvy - sh.s[ar][3];
    const float dist = sqrtf(fmaf(rx, rx, ry * ry));
    const float sx = (rx == 0.f && ry == 0.f) ? 1.f : rx;
    const float ang = fast_atan2(ry, sx);
    const float sd  = sqrtf(fmaf(dvx, dvx, dvy * dvy));
    q0[r] = (unsigned)f2bf(dist) | ((unsigned)f2bf(ang) << 16);
    q1[r] = (unsigned)f2bf(sd) | mbits;
  }
  if (hastail) {                       // tail row geo
    const int ar = ar4;
    const float rx  = pbx - sh.s[ar][0], ry  = pby - sh.s[ar][1];
    const float dvx = pvx - sh.s[ar][2], dvy = pvy - sh.s[ar][3];
    const float dist = sqrtf(fmaf(rx, rx, ry * ry));
    const float sx = (rx == 0.f && ry == 0.f) ? 1.f : rx;
    const float ang = fast_atan2(ry, sx);
    const float sd  = sqrtf(fmaf(dvx, dvx, dvy * dvy));
    q0t = (unsigned)f2bf(dist) | ((unsigned)f2bf(ang) << 16);
    q1t = (unsigned)f2bf(sd) | mbits;
  }

  // ---------------- Phase 1: agent_feat = relu(s @ w_a + b_a) -------------
  {
    #pragma unroll
    for (int r = 0; r < RPT; ++r) {
      const int a = bg + NG * r;
      if (a < KA) {
        const float* srow = sh.s[a];
        float v = fmaf(srow[0], wa0, fmaf(srow[1], wa1, fmaf(srow[2], wa2,
                  fmaf(srow[3], wa3, fmaf(srow[4], wa4, fmaf(srow[5], wa5, bac))))));
        sh.af[a * STRD + c] = f2bf(fmaxf(v, 0.f));
      }
    }
  }
  // ---- Phase-2 B-fragment prefetch (global; barrier wait covers latency) --
  bf16x8 Bi[4], Bj[4];
  #pragma unroll
  for (int kt = 0; kt < 4; ++kt) {
    Bi[kt] = *(const bf16x8*)&wp[(size_t)((WS_WI + kt*8 + ct) * 64 + lane) * 8];
    Bj[kt] = *(const bf16x8*)&wp[(size_t)((WS_WJ + kt*8 + ct) * 64 + lane) * 8];
  }
  __syncthreads();
  if (tid < KP) {
    const float ca = (tid < KA) ? sh.m[tid] * sh.cnt : 0.f;
    sh.cnta[tid] = ca;
    sh.invden[tid] = 1.0f / fmaxf(ca, 1.0f);
  }

  // ---------------- Phase 2 (MFMA): xi = af@wi, xj = af@wj ----------------
  {
    f32x4 ci0 = {0,0,0,0}, ci1 = {0,0,0,0}, cj0 = {0,0,0,0}, cj1 = {0,0,0,0};
    #pragma unroll
    for (int kt = 0; kt < 4; ++kt) {
      const bf16x8 A0 = *(const bf16x8*)&sh.af[(rtb*16 + fr) * STRD + kt*32 + fkg*8];
      const bf16x8 A1 = *(const bf16x8*)&sh.af[((rtb+1)*16 + fr) * STRD + kt*32 + fkg*8];
      ci0 = __builtin_amdgcn_mfma_f32_16x16x32_bf16(A0, Bi[kt], ci0, 0, 0, 0);
      ci1 = __builtin_amdgcn_mfma_f32_16x16x32_bf16(A1, Bi[kt], ci1, 0, 0, 0);
      cj0 = __builtin_amdgcn_mfma_f32_16x16x32_bf16(A0, Bj[kt], cj0, 0, 0, 0);
      cj1 = __builtin_amdgcn_mfma_f32_16x16x32_bf16(A1, Bj[kt], cj1, 0, 0, 0);
    }
    #pragma unroll
    for (int rt2 = 0; rt2 < 2; ++rt2) {
      const f32x4 vi = rt2 ? ci1 : ci0;
      const f32x4 vj = rt2 ? cj1 : cj0;
      #pragma unroll
      for (int g = 0; g < 4; ++g) {
        const int r = (rtb + rt2) * 16 + fkg * 4 + g;
        if (r < KP) {
          sh.xi[r * STRD + col] = f2bf(vi[g]);
          sh.xj[r * H + col]    = f2bf(vj[g]);
        }
      }
    }
  }
  __syncthreads();

  // ------ Phase 3: pair loop -> hsum (tails spread over 8 waves) ----------
  {
    v2f base01[3], acc01[3];
    #pragma unroll
    for (int r = 0; r < 3; ++r) {
      const int ar = wid + 16 * r;
      const unsigned xip = *(const unsigned*)&sh.xi[ar * STRD + c0];
      base01[r] = (v2f){ bf2f((unsigned short)xip), bf2f((unsigned short)(xip >> 16)) } + br101;
      acc01[r] = (v2f){0.f, 0.f};
    }
    ph3_main(sh, q0, q1, base01, acc01, wgd01, wgan01, wgs01, c0);
    #pragma unroll
    for (int r = 0; r < 3; ++r) {
      const int ar = wid + 16 * r;
      const float ma = sh.m[ar];
      *(unsigned*)&sh.hsum[ar * STRD + c0] =
          (unsigned)f2bf(acc01[r].x * ma) | ((unsigned)f2bf(acc01[r].y * ma) << 16);
    }
    if (hastail) {
      const unsigned xip = *(const unsigned*)&sh.xi[ar4 * STRD + c0];
      const v2f baset = (v2f){ bf2f((unsigned short)xip),
                               bf2f((unsigned short)(xip >> 16)) } + br101;
      v2f acct = {0.f, 0.f};
      if (chunk < 2) ph3_tail<13>(sh, bbeg, q0t, q1t, baset, acct, wgd01, wgan01, wgs01, c0);
      else           ph3_tail<12>(sh, bbeg, q0t, q1t, baset, acct, wgd01, wgan01, wgs01, c0);
      *(float2*)&sh.red[wid * H + c0] = make_float2(acct.x, acct.y);   // raw partial
    }
  }
  __syncthreads();
  // combine rows 48,49 from the 4 chunk partials each
  if (tid < 256) {
    const int rr = tid >> 7;            // 0: row 48, 1: row 49
    const int cc = tid & 127;
    const float v = ((sh.red[rr * H + cc]       + sh.red[(rr + 2) * H + cc]) +
                     (sh.red[(rr + 4) * H + cc] + sh.red[(rr + 6) * H + cc])) *
                    sh.m[48 + rr];
    sh.hsum[(48 + rr) * STRD + cc] = f2bf(v);
  }
  __syncthreads();

  // ------ Phase 4 + 5a (MFMA): agg = hsum@wr2 ; combined-af = af@wg[0:128] -
  f32x4 p0 = {0,0,0,0}, p1 = {0,0,0,0};   // ph5 accumulators (af part first)
  {
    f32x4 a0 = {0,0,0,0}, a1 = {0,0,0,0};
    #pragma unroll
    for (int kt = 0; kt < 4; ++kt) {
      const bf16x8 B4 = *(const bf16x8*)&wp[(size_t)((WS_WR2 + kt*8 + ct) * 64 + lane) * 8];
      const bf16x8 A0h = *(const bf16x8*)&sh.hsum[(rtb*16 + fr) * STRD + kt*32 + fkg*8];
      const bf16x8 A1h = *(const bf16x8*)&sh.hsum[((rtb+1)*16 + fr) * STRD + kt*32 + fkg*8];
      a0 = __builtin_amdgcn_mfma_f32_16x16x32_bf16(A0h, B4, a0, 0, 0, 0);
      a1 = __builtin_amdgcn_mfma_f32_16x16x32_bf16(A1h, B4, a1, 0, 0, 0);
      const bf16x8 B5 = *(const bf16x8*)&wp[(size_t)((WS_WG + kt*8 + ct) * 64 + lane) * 8];
      const bf16x8 A0a = *(const bf16x8*)&sh.af[(rtb*16 + fr) * STRD + kt*32 + fkg*8];
      const bf16x8 A1a = *(const bf16x8*)&sh.af[((rtb+1)*16 + fr) * STRD + kt*32 + fkg*8];
      p0 = __builtin_amdgcn_mfma_f32_16x16x32_bf16(A0a, B5, p0, 0, 0, 0);
      p1 = __builtin_amdgcn_mfma_f32_16x16x32_bf16(A1a, B5, p1, 0, 0, 0);
    }
    const float br2c = b_r2[col];
    #pragma unroll
    for (int rt2 = 0; rt2 < 2; ++rt2) {
      const f32x4 v = rt2 ? a1 : a0;
      #pragma unroll
      for (int g = 0; g < 4; ++g) {
        const int r = (rtb + rt2) * 16 + fkg * 4 + g;
        if (r < KP) {
          const float val = fmaf(sh.cnta[r], br2c, v[g]) * sh.invden[r];
          sh.xi[r * STRD + col] = f2bf(val);   // xi now holds agg
        }
      }
    }
  }
  __syncthreads();

  // ---------------- Phase 5b (MFMA): + agg@wg[128:256]; pool --------------
  {
    #pragma unroll
    for (int kt = 0; kt < 4; ++kt) {
      const bf16x8 B = *(const bf16x8*)&wp[(size_t)((WS_WG + (kt+4)*8 + ct) * 64 + lane) * 8];
      const bf16x8 A0 = *(const bf16x8*)&sh.xi[(rtb*16 + fr) * STRD + kt*32 + fkg*8];
      const bf16x8 A1 = *(const bf16x8*)&sh.xi[((rtb+1)*16 + fr) * STRD + kt*32 + fkg*8];
      p0 = __builtin_amdgcn_mfma_f32_16x16x32_bf16(A0, B, p0, 0, 0, 0);
      p1 = __builtin_amdgcn_mfma_f32_16x16x32_bf16(A1, B, p1, 0, 0, 0);
    }
    const float bgc = b_g[col];
    float pv = 0.f;
    #pragma unroll
    for (int rt2 = 0; rt2 < 2; ++rt2) {
      const f32x4 v = rt2 ? p1 : p0;
      #pragma unroll
      for (int g = 0; g < 4; ++g) {
        const int r = (rtb + rt2) * 16 + fkg * 4 + g;
        if (r < KA) {
          pv = fmaf(sh.m[r], fmaxf(v[g] + bgc, 0.f), pv);
        }
      }
    }
    pv += __shfl_xor(pv, 16);
    pv += __shfl_xor(pv, 32);
    if (lane < 16) sh.red[(wid >> 3) * H + col] = pv;
  }
  __syncthreads();

  // ---- Phase 6 (pooled folded in by linearity): partials -> xi scratch ----
  float* scr = (float*)sh.xi;          // 1024 f32 scratch; xi dead after 5b
  const int d67 = tid & (D - 1);
  const int hh67 = tid >> 8;           // 0..3
  {
    const float invp = 1.0f / fmaxf(sh.cnt, 1.0f);
    const float* wf = w_f1 + d67;
    float acc = 0.f;
    const int k0 = hh67 * 32;
    #pragma unroll 8
    for (int k = 0; k < 32; ++k)
      acc = fmaf(sh.red[k0 + k] + sh.red[H + k0 + k], wf[(k0 + k) * D], acc);
    scr[hh67 * D + d67] = acc * invp;
  }
  __syncthreads();
  if (tid < D) {
    sh.latent1[tid] = fmaxf(scr[tid] + scr[D + tid] +
                            scr[2*D + tid] + scr[3*D + tid] +
                            b_f1[tid], 0.f);
  }
  __syncthreads();

  // ---------------- Phase 7: out = latent1 @ w_f2 + b_f2 ------------------
  {
    const float* wf = w_f2 + d67;
    float acc = 0.f;
    const int k0 = hh67 * 64;
    #pragma unroll 8
    for (int k = 0; k < 64; ++k)
      acc = fmaf(sh.latent1[k0 + k], wf[(k0 + k) * D], acc);
    sh.red[hh67 * D + d67] = acc;     // latent1 != red: no hazard
  }
  __syncthreads();
  if (tid < D) {
    out[(size_t)n * D + tid] = sh.red[tid] + sh.red[D + tid] +
                               sh.red[2*D + tid] + sh.red[3*D + tid] +
                               b_f2[tid];
  }
}

extern "C" void kernel_launch(void* const* d_in, const int* in_sizes, int n_in,
                              void* d_out, int out_size, void* d_ws, size_t ws_size,
                              hipStream_t stream) {
  const float* states = (const float*)d_in[0];
  const float* masks  = (const float*)d_in[1];
  const float* w_a  = (const float*)d_in[2];
  const float* b_a  = (const float*)d_in[3];
  const float* w_r1 = (const float*)d_in[4];
  const float* b_r1 = (const float*)d_in[5];
  const float* w_r2 = (const float*)d_in[6];
  const float* b_r2 = (const float*)d_in[7];
  const float* w_g  = (const float*)d_in[8];
  const float* b_g  = (const float*)d_in[9];
  const float* w_f1 = (const float*)d_in[10];
  const float* b_f1 = (const float*)d_in[11];
  const float* w_f2 = (const float*)d_in[12];
  const float* b_f2 = (const float*)d_in[13];
  float* out = (float*)d_out;
  unsigned short* wp = (unsigned short*)d_ws;

  hipLaunchKernelGGL(pack_weights, dim3((NFRAG * 64 + 255) / 256), dim3(256), 0, stream,
                     w_r1, w_r2, w_g, wp);
  hipLaunchKernelGGL(rpe_kernel, dim3(NBLK), dim3(BLOCK), 0, stream,
                     states, masks, w_a, b_a, w_r1, b_r1, b_r2,
                     b_g, w_f1, b_f1, w_f2, b_f2, wp, out);
}

// Round 17
// 36.164 us; speedup vs baseline: 1.0275x; 1.0275x over previous
//
#include <hip/hip_runtime.h>

#define KA 50
#define KP 52
#define H 128
#define D 256
#define NBLK 256
#define BLOCK 1024
#define NG 8
#define RPT 7
#define STRD 136   // shorts; row stride for af/xi/hsum (272B: 16B-aligned, 2-way bank alias)

// B-fragment pack bases (units of 512-short fragments)
#define WS_WI 0
#define WS_WJ 32
#define WS_WR2 64
#define WS_WG 96
#define NFRAG 160

typedef __attribute__((ext_vector_type(8))) short bf16x8;
typedef __attribute__((ext_vector_type(4))) float f32x4;
typedef __attribute__((ext_vector_type(2))) float v2f;

__device__ __forceinline__ float bf2f(unsigned short u) {
  return __uint_as_float(((unsigned)u) << 16);
}
__device__ __forceinline__ unsigned short f2bf_rne(float f) {   // pack_weights only
  unsigned u = __float_as_uint(f);
  u = (u + 0x7FFFu + ((u >> 16) & 1u)) >> 16;
  return (unsigned short)u;
}
__device__ __forceinline__ unsigned short f2bf(float f) {   // RN ties-away, 2 ops
  return (unsigned short)((__float_as_uint(f) + 0x8000u) >> 16);
}
__device__ __forceinline__ int rli(int v, int l) {   // wave broadcast
  return __builtin_amdgcn_readlane(v, l);
}
// atan2 via odd minimax poly on [0,1]; |err| ~1e-5 rad (<< bf16 quant of ang).
// Callers guarantee (x,y) != (0,0).
__device__ __forceinline__ float fast_atan2(float y, float x) {
  const float ax = fabsf(x), ay = fabsf(y);
  const float mx = fmaxf(ax, ay), mn = fminf(ax, ay);
  const float r  = mn * __builtin_amdgcn_rcpf(mx);
  const float r2 = r * r;
  float p = fmaf(r2, 0.0208351f, -0.0851330f);
  p = fmaf(r2, p, 0.1801410f);
  p = fmaf(r2, p, -0.3302995f);
  p = fmaf(r2, p, 0.9998660f);
  float th = r * p;
  if (ay > ax) th = 1.57079632679f - th;
  if (x < 0.f) th = 3.14159265359f - th;
  return copysignf(th, y);
}

// ---- pre-pass: pack weights into bf16 MFMA B-fragment order in d_ws ------
__global__ void pack_weights(const float* __restrict__ w_r1,
                             const float* __restrict__ w_r2,
                             const float* __restrict__ w_g,
                             unsigned short* __restrict__ wp) {
  const int t = blockIdx.x * 256 + threadIdx.x;
  if (t >= NFRAG * 64) return;
  const int f = t >> 6, lane = t & 63;
  const float* W; int rowbase, sf;
  if (f < 64)       { W = w_r1; rowbase = (f < 32) ? 0 : 128; sf = f & 31; }
  else if (f < 96)  { W = w_r2; rowbase = 0; sf = f - 64; }
  else              { W = w_g;  rowbase = 0; sf = f - 96; }
  const int kt = sf >> 3, ctl = sf & 7;
  const int col = ctl * 16 + (lane & 15);
  const int k0  = rowbase + kt * 32 + (lane >> 4) * 8;
  unsigned short v[8];
  #pragma unroll
  for (int j = 0; j < 8; ++j) v[j] = f2bf_rne(W[(k0 + j) * H + col]);
  #pragma unroll
  for (int j = 0; j < 8; ++j) wp[(size_t)t * 8 + j] = v[j];
}

struct alignas(16) Smem {
  unsigned short af[KP * STRD];    // agent_feat bf16 (rows 50,51 zeroed)
  unsigned short xi[KP * STRD];    // x_i bf16; agg after ph4; f32 scratch in ph6
  unsigned short xj[KP * H];       // x_j bf16, row-major [52][128]
  unsigned short hsum[KP * STRD];  // masked relu-sum over b, bf16
  float red[1024];
  float latent1[D];
  float s[KA][6];
  float m[64];                     // zero-padded
  float cnta[KP];
  float invden[KP];
  float cnt;
};

// phase-3 half-loop (b in [bbeg, bbeg+25)) for NR accumulator rows
template <int NR>
__device__ __forceinline__ void ph3_half(const Smem& sh, int bbeg,
                                         const unsigned* q0, const unsigned* q1,
                                         const v2f* base01, v2f* acc01,
                                         v2f wgd01, v2f wgan01, v2f wgs01,
                                         int c0) {
  #pragma unroll 5
  for (int bi = 0; bi < 25; ++bi) {
    const int b = bbeg + bi;
    const unsigned xjp = *(const unsigned*)&sh.xj[b * H + c0];
    const v2f xj01 = { __uint_as_float(xjp << 16),
                       __uint_as_float(xjp & 0xFFFF0000u) };
    #pragma unroll
    for (int r = 0; r < NR; ++r) {
      const unsigned rq0 = (unsigned)rli((int)q0[r], b);
      const unsigned rq1 = (unsigned)rli((int)q1[r], b);
      const float dd = __uint_as_float(rq0 << 16);
      const float aa = __uint_as_float(rq0 & 0xFFFF0000u);
      const float ss = __uint_as_float(rq1 << 16);
      const float mm = __uint_as_float(rq1 & 0xFFFF0000u);
      v2f t = __builtin_elementwise_fma((v2f){dd, dd}, wgd01, base01[r] + xj01);
      t = __builtin_elementwise_fma((v2f){aa, aa}, wgan01, t);
      t = __builtin_elementwise_fma((v2f){ss, ss}, wgs01, t);
      t = __builtin_elementwise_max(t, (v2f){0.f, 0.f});
      acc01[r] = __builtin_elementwise_fma((v2f){mm, mm}, t, acc01[r]);
    }
  }
}

__global__ void __launch_bounds__(BLOCK) rpe_kernel(
    const float* __restrict__ states, const float* __restrict__ masks,
    const float* __restrict__ w_a,  const float* __restrict__ b_a,
    const float* __restrict__ w_r1, const float* __restrict__ b_r1,
    const float* __restrict__ b_r2,
    const float* __restrict__ b_g,
    const float* __restrict__ w_f1, const float* __restrict__ b_f1,
    const float* __restrict__ w_f2, const float* __restrict__ b_f2,
    const unsigned short* __restrict__ wp,
    float* __restrict__ out) {
  __shared__ Smem sh;
  const int n = blockIdx.x;
  const int tid = threadIdx.x;
  const int c = tid & (H - 1);
  const int bg = tid >> 7;            // 0..7
  const int wid = tid >> 6, lane = tid & 63;
  const int ct = wid & 7;             // col tile 0..7 (MFMA phases)
  const int rtb = (wid >> 3) * 2;     // row tiles rtb, rtb+1
  const int fr = lane & 15;
  const int fkg = lane >> 4;
  const int col = ct * 16 + fr;

  // ---- top-level preloads (no LDS dependence) ----------------------------
  const float bac = b_a[c];
  const float wa0 = w_a[0*H+c], wa1 = w_a[1*H+c], wa2 = w_a[2*H+c];
  const float wa3 = w_a[3*H+c], wa4 = w_a[4*H+c], wa5 = w_a[5*H+c];
  const int c0 = 2 * lane;
  const v2f wgd01  = { w_r1[256*H + c0], w_r1[256*H + c0+1] };
  const v2f wgan01 = { w_r1[257*H + c0], w_r1[257*H + c0+1] };
  const v2f wgs01  = { w_r1[258*H + c0], w_r1[258*H + c0+1] };
  const v2f br101  = { b_r1[c0], b_r1[c0+1] };

  // ---------------- Phase 0: stage states, masks, zero pads ---------------
  {
    if (tid < KA * 6) ((float*)sh.s)[tid] = states[(size_t)n * (KA * 6) + tid];
    if (tid < 64) sh.m[tid] = (tid < KA) ? masks[(size_t)n * KA + tid] : 0.f;
    if (tid < 2 * H) {
      const int r5 = KA + (tid >> 7), cc = tid & (H - 1);
      sh.af[r5 * STRD + cc] = 0;
      sh.hsum[r5 * STRD + cc] = 0;
    }
  }
  __syncthreads();
  if (wid == 0) {                     // parallel mask count (lanes 50-63 are 0)
    float v = sh.m[lane];
    v += __shfl_xor(v, 1);  v += __shfl_xor(v, 2);  v += __shfl_xor(v, 4);
    v += __shfl_xor(v, 8);  v += __shfl_xor(v, 16); v += __shfl_xor(v, 32);
    if (lane == 0) sh.cnt = v;
  }

  // ---- Phase-3 geo hoist: lane b owns geo(a_rows, b), bf16-packed --------
  const int bl = (lane < KA) ? lane : (KA - 1);
  const float pbx = sh.s[bl][0], pby = sh.s[bl][1];
  const float pvx = sh.s[bl][2], pvy = sh.s[bl][3];
  const unsigned mbits = (sh.m[lane] != 0.f) ? 0x3F800000u : 0u;  // bf16 1.0 hi
  const bool has4 = (wid < 4);        // waves 0,1: row 48 halves; 2,3: row 49
  const int ar4 = 48 + ((wid >> 1) & 1);
  unsigned q0[4], q1[4];
  q0[3] = 0; q1[3] = 0;
  #pragma unroll
  for (int r = 0; r < 3; ++r) {
    const int ar = wid + 16 * r;       // <= 47
    const float rx  = pbx - sh.s[ar][0], ry  = pby - sh.s[ar][1];
    const float dvx = pvx - sh.s[ar][2], dvy = pvy - sh.s[ar][3];
    const float dist = sqrtf(fmaf(rx, rx, ry * ry));
    const float sx = (rx == 0.f && ry == 0.f) ? 1.f : rx;
    const float ang = fast_atan2(ry, sx);
    const float sd  = sqrtf(fmaf(dvx, dvx, dvy * dvy));
    q0[r] = (unsigned)f2bf(dist) | ((unsigned)f2bf(ang) << 16);
    q1[r] = (unsigned)f2bf(sd) | mbits;
  }
  if (has4) {                          // 4th row: 48 (waves 0,1) or 49 (2,3)
    const int ar = ar4;
    const float rx  = pbx - sh.s[ar][0], ry  = pby - sh.s[ar][1];
    const float dvx = pvx - sh.s[ar][2], dvy = pvy - sh.s[ar][3];
    const float dist = sqrtf(fmaf(rx, rx, ry * ry));
    const float sx = (rx == 0.f && ry == 0.f) ? 1.f : rx;
    const float ang = fast_atan2(ry, sx);
    const float sd  = sqrtf(fmaf(dvx, dvx, dvy * dvy));
    q0[3] = (unsigned)f2bf(dist) | ((unsigned)f2bf(ang) << 16);
    q1[3] = (unsigned)f2bf(sd) | mbits;
  }

  // ---------------- Phase 1: agent_feat = relu(s @ w_a + b_a) -------------
  {
    #pragma unroll
    for (int r = 0; r < RPT; ++r) {
      const int a = bg + NG * r;
      if (a < KA) {
        const float* srow = sh.s[a];
        float v = fmaf(srow[0], wa0, fmaf(srow[1], wa1, fmaf(srow[2], wa2,
                  fmaf(srow[3], wa3, fmaf(srow[4], wa4, fmaf(srow[5], wa5, bac))))));
        sh.af[a * STRD + c] = f2bf(fmaxf(v, 0.f));
      }
    }
  }
  // ---- Phase-2 B-fragment prefetch (global; barrier wait covers latency) --
  bf16x8 Bi[4], Bj[4];
  #pragma unroll
  for (int kt = 0; kt < 4; ++kt) {
    Bi[kt] = *(const bf16x8*)&wp[(size_t)((WS_WI + kt*8 + ct) * 64 + lane) * 8];
    Bj[kt] = *(const bf16x8*)&wp[(size_t)((WS_WJ + kt*8 + ct) * 64 + lane) * 8];
  }
  __syncthreads();
  if (tid < KP) {
    const float ca = (tid < KA) ? sh.m[tid] * sh.cnt : 0.f;
    sh.cnta[tid] = ca;
    sh.invden[tid] = 1.0f / fmaxf(ca, 1.0f);
  }

  // ---------------- Phase 2 (MFMA): xi = af@wi, xj = af@wj ----------------
  {
    f32x4 ci0 = {0,0,0,0}, ci1 = {0,0,0,0}, cj0 = {0,0,0,0}, cj1 = {0,0,0,0};
    #pragma unroll
    for (int kt = 0; kt < 4; ++kt) {
      const bf16x8 A0 = *(const bf16x8*)&sh.af[(rtb*16 + fr) * STRD + kt*32 + fkg*8];
      const bf16x8 A1 = *(const bf16x8*)&sh.af[((rtb+1)*16 + fr) * STRD + kt*32 + fkg*8];
      ci0 = __builtin_amdgcn_mfma_f32_16x16x32_bf16(A0, Bi[kt], ci0, 0, 0, 0);
      ci1 = __builtin_amdgcn_mfma_f32_16x16x32_bf16(A1, Bi[kt], ci1, 0, 0, 0);
      cj0 = __builtin_amdgcn_mfma_f32_16x16x32_bf16(A0, Bj[kt], cj0, 0, 0, 0);
      cj1 = __builtin_amdgcn_mfma_f32_16x16x32_bf16(A1, Bj[kt], cj1, 0, 0, 0);
    }
    #pragma unroll
    for (int rt2 = 0; rt2 < 2; ++rt2) {
      const f32x4 vi = rt2 ? ci1 : ci0;
      const f32x4 vj = rt2 ? cj1 : cj0;
      #pragma unroll
      for (int g = 0; g < 4; ++g) {
        const int r = (rtb + rt2) * 16 + fkg * 4 + g;
        if (r < KP) {
          sh.xi[r * STRD + col] = f2bf(vi[g]);
          sh.xj[r * H + col]    = f2bf(vj[g]);
        }
      }
    }
  }
  __syncthreads();

  // ------ Phase 3: pair loop -> hsum (balanced: tail rows split in b) -----
  {
    v2f base01[4], acc01[4];
    #pragma unroll
    for (int r = 0; r < 4; ++r) {
      const int ar = (r < 3) ? (wid + 16 * r) : ar4;
      const unsigned xip = *(const unsigned*)&sh.xi[ar * STRD + c0];
      base01[r] = (v2f){ bf2f((unsigned short)xip), bf2f((unsigned short)(xip >> 16)) } + br101;
      acc01[r] = (v2f){0.f, 0.f};
    }
    if (has4) {
      if (wid & 1) {   // second half of b carries the 4th row
        ph3_half<3>(sh, 0,  q0, q1, base01, acc01, wgd01, wgan01, wgs01, c0);
        ph3_half<4>(sh, 25, q0, q1, base01, acc01, wgd01, wgan01, wgs01, c0);
      } else {         // first half of b carries the 4th row
        ph3_half<4>(sh, 0,  q0, q1, base01, acc01, wgd01, wgan01, wgs01, c0);
        ph3_half<3>(sh, 25, q0, q1, base01, acc01, wgd01, wgan01, wgs01, c0);
      }
    } else {
      ph3_half<3>(sh, 0,  q0, q1, base01, acc01, wgd01, wgan01, wgs01, c0);
      ph3_half<3>(sh, 25, q0, q1, base01, acc01, wgd01, wgan01, wgs01, c0);
    }
    #pragma unroll
    for (int r = 0; r < 3; ++r) {
      const int ar = wid + 16 * r;
      const float ma = sh.m[ar];
      *(unsigned*)&sh.hsum[ar * STRD + c0] =
          (unsigned)f2bf(acc01[r].x * ma) | ((unsigned)f2bf(acc01[r].y * ma) << 16);
    }
    if (has4) {       // raw half-range partials -> red (mask applied at combine)
      *(float2*)&sh.red[wid * H + c0] = make_float2(acc01[3].x, acc01[3].y);
    }
  }
  __syncthreads();
  // combine rows 48,49 from the wave-half partials
  if (tid < 256) {
    const int rr = tid >> 7;            // 0: row 48, 1: row 49
    const int cc = tid & 127;
    const float v = (sh.red[(rr * 2) * H + cc] + sh.red[(rr * 2 + 1) * H + cc]) *
                    sh.m[48 + rr];
    sh.hsum[(48 + rr) * STRD + cc] = f2bf(v);
  }
  __syncthreads();

  // ------ Phase 4 + 5a (MFMA): agg = hsum@wr2 ; combined-af = af@wg[0:128] -
  f32x4 p0 = {0,0,0,0}, p1 = {0,0,0,0};   // ph5 accumulators (af part first)
  {
    f32x4 a0 = {0,0,0,0}, a1 = {0,0,0,0};
    #pragma unroll
    for (int kt = 0; kt < 4; ++kt) {
      const bf16x8 B4 = *(const bf16x8*)&wp[(size_t)((WS_WR2 + kt*8 + ct) * 64 + lane) * 8];
      const bf16x8 A0h = *(const bf16x8*)&sh.hsum[(rtb*16 + fr) * STRD + kt*32 + fkg*8];
      const bf16x8 A1h = *(const bf16x8*)&sh.hsum[((rtb+1)*16 + fr) * STRD + kt*32 + fkg*8];
      a0 = __builtin_amdgcn_mfma_f32_16x16x32_bf16(A0h, B4, a0, 0, 0, 0);
      a1 = __builtin_amdgcn_mfma_f32_16x16x32_bf16(A1h, B4, a1, 0, 0, 0);
      const bf16x8 B5 = *(const bf16x8*)&wp[(size_t)((WS_WG + kt*8 + ct) * 64 + lane) * 8];
      const bf16x8 A0a = *(const bf16x8*)&sh.af[(rtb*16 + fr) * STRD + kt*32 + fkg*8];
      const bf16x8 A1a = *(const bf16x8*)&sh.af[((rtb+1)*16 + fr) * STRD + kt*32 + fkg*8];
      p0 = __builtin_amdgcn_mfma_f32_16x16x32_bf16(A0a, B5, p0, 0, 0, 0);
      p1 = __builtin_amdgcn_mfma_f32_16x16x32_bf16(A1a, B5, p1, 0, 0, 0);
    }
    const float br2c = b_r2[col];
    #pragma unroll
    for (int rt2 = 0; rt2 < 2; ++rt2) {
      const f32x4 v = rt2 ? a1 : a0;
      #pragma unroll
      for (int g = 0; g < 4; ++g) {
        const int r = (rtb + rt2) * 16 + fkg * 4 + g;
        if (r < KP) {
          const float val = fmaf(sh.cnta[r], br2c, v[g]) * sh.invden[r];
          sh.xi[r * STRD + col] = f2bf(val);   // xi now holds agg
        }
      }
    }
  }
  __syncthreads();

  // ---------------- Phase 5b (MFMA): + agg@wg[128:256]; pool --------------
  {
    #pragma unroll
    for (int kt = 0; kt < 4; ++kt) {
      const bf16x8 B = *(const bf16x8*)&wp[(size_t)((WS_WG + (kt+4)*8 + ct) * 64 + lane) * 8];
      const bf16x8 A0 = *(const bf16x8*)&sh.xi[(rtb*16 + fr) * STRD + kt*32 + fkg*8];
      const bf16x8 A1 = *(const bf16x8*)&sh.xi[((rtb+1)*16 + fr) * STRD + kt*32 + fkg*8];
      p0 = __builtin_amdgcn_mfma_f32_16x16x32_bf16(A0, B, p0, 0, 0, 0);
      p1 = __builtin_amdgcn_mfma_f32_16x16x32_bf16(A1, B, p1, 0, 0, 0);
    }
    const float bgc = b_g[col];
    float pv = 0.f;
    #pragma unroll
    for (int rt2 = 0; rt2 < 2; ++rt2) {
      const f32x4 v = rt2 ? p1 : p0;
      #pragma unroll
      for (int g = 0; g < 4; ++g) {
        const int r = (rtb + rt2) * 16 + fkg * 4 + g;
        if (r < KA) {
          pv = fmaf(sh.m[r], fmaxf(v[g] + bgc, 0.f), pv);
        }
      }
    }
    pv += __shfl_xor(pv, 16);
    pv += __shfl_xor(pv, 32);
    if (lane < 16) sh.red[(wid >> 3) * H + col] = pv;
  }
  __syncthreads();

  // ---- Phase 6 (pooled folded in by linearity): partials -> xi scratch ----
  float* scr = (float*)sh.xi;          // 1024 f32 scratch; xi dead after 5b
  const int d67 = tid & (D - 1);
  const int hh67 = tid >> 8;           // 0..3
  {
    const float invp = 1.0f / fmaxf(sh.cnt, 1.0f);
    const float* wf = w_f1 + d67;
    float acc = 0.f;
    const int k0 = hh67 * 32;
    #pragma unroll 8
    for (int k = 0; k < 32; ++k)
      acc = fmaf(sh.red[k0 + k] + sh.red[H + k0 + k], wf[(k0 + k) * D], acc);
    scr[hh67 * D + d67] = acc * invp;
  }
  __syncthreads();
  if (tid < D) {
    sh.latent1[tid] = fmaxf(scr[tid] + scr[D + tid] +
                            scr[2*D + tid] + scr[3*D + tid] +
                            b_f1[tid], 0.f);
  }
  __syncthreads();

  // ---------------- Phase 7: out = latent1 @ w_f2 + b_f2 ------------------
  {
    const float* wf = w_f2 + d67;
    float acc = 0.f;
    const int k0 = hh67 * 64;
    #pragma unroll 8
    for (int k = 0; k < 64; ++k)
      acc = fmaf(sh.latent1[k0 + k], wf[(k0 + k) * D], acc);
    sh.red[hh67 * D + d67] = acc;     // latent1 != red: no hazard
  }
  __syncthreads();
  if (tid < D) {
    out[(size_t)n * D + tid] = sh.red[tid] + sh.red[D + tid] +
                               sh.red[2*D + tid] + sh.red[3*D + tid] +
                               b_f2[tid];
  }
}

extern "C" void kernel_launch(void* const* d_in, const int* in_sizes, int n_in,
                              void* d_out, int out_size, void* d_ws, size_t ws_size,
                              hipStream_t stream) {
  const float* states = (const float*)d_in[0];
  const float* masks  = (const float*)d_in[1];
  const float* w_a  = (const float*)d_in[2];
  const float* b_a  = (const float*)d_in[3];
  const float* w_r1 = (const float*)d_in[4];
  const float* b_r1 = (const float*)d_in[5];
  const float* w_r2 = (const float*)d_in[6];
  const float* b_r2 = (const float*)d_in[7];
  const float* w_g  = (const float*)d_in[8];
  const float* b_g  = (const float*)d_in[9];
  const float* w_f1 = (const float*)d_in[10];
  const float* b_f1 = (const float*)d_in[11];
  const float* w_f2 = (const float*)d_in[12];
  const float* b_f2 = (const float*)d_in[13];
  float* out = (float*)d_out;
  unsigned short* wp = (unsigned short*)d_ws;

  hipLaunchKernelGGL(pack_weights, dim3((NFRAG * 64 + 255) / 256), dim3(256), 0, stream,
                     w_r1, w_r2, w_g, wp);
  hipLaunchKernelGGL(rpe_kernel, dim3(NBLK), dim3(BLOCK), 0, stream,
                     states, masks, w_a, b_a, w_r1, b_r1, b_r2,
                     b_g, w_f1, b_f1, w_f2, b_f2, wp, out);
}